// Round 8
// baseline (392.980 us; speedup 1.0000x reference)
//
#include <hip/hip_runtime.h>
#include <hip/hip_bf16.h>

// Problem constants
#define TDATA 100000
#define NE 500
#define NI 200
#define SUB 20
#define NB 3
#define TSYN 201

// Layout
#define SROW 100552              // 200 front pad + data + 352 tail pad
#define HROW 216                 // conv taps padded: k in [-8,207] at [k+8]
#define NSTEP_E 32               // K=500 -> 32 MFMA k-steps (zero-padded)
#define NSTEP_I 13               // K=200 -> 13 k-steps
#define NF4_E 4000               // 32*500/4 float4s per e-tile (64000 B)
#define NF4_I 1600               // 32*200/4 float4s per i-tile (25600 B)
#define NTILE 3125               // 100000/32 exactly, per matrix
#define NBE 366                  // persistent e-blocks (71.4% of 512, byte-balanced)
#define NBI 146                  // persistent i-blocks

// ws float offsets
#define OFF_HP  0                            // 2*20*216 = 8640 floats
#define OFF_BE  8640                         // e A-frags: 32*64*8 bf16 = 8192 float slots
#define OFF_BI  (OFF_BE + 8192)              // 16832; i A-frags: 14*64*8 bf16 = 3584 slots
#define OFF_INT (OFF_BI + 3584)              // 20416; inT = 40 rows x SROW

typedef __bf16 bf16x8 __attribute__((ext_vector_type(8)));
typedef __bf16 bf16x4 __attribute__((ext_vector_type(4)));
typedef float  f32x16 __attribute__((ext_vector_type(16)));

// ---------------------------------------------------------------------------
// Setup: conv taps | inT pad zeros | bf16 A-operand fragments (exact MFMA
// per-lane order: element j of lane l, k-step u -> C[s=l&31][k=16u+8*(l>>5)+j])
// Grid = 212*256 = 54272 exactly.  (unchanged — passed 8 rounds)
// ---------------------------------------------------------------------------
__global__ __launch_bounds__(256) void setup_kernel(
    const float* __restrict__ C_e, const float* __restrict__ C_i,
    const float* __restrict__ K_syn, const float* __restrict__ tau_syn,
    const float* __restrict__ delta_syn, float* __restrict__ ws)
{
    int idx = blockIdx.x * 256 + threadIdx.x;
    if (idx < 8640) {                        // ---- conv taps (zero-padded)
        int c = idx / (SUB * HROW);
        int rem = idx - c * (SUB * HROW);
        int s = rem / HROW;
        int k = (rem - s * HROW) - 8;
        float v = 0.f;
        if (k >= 0 && k < TSYN) {
            float ts = (float)k - delta_syn[s * 2 + c];
            ts = ts < 0.f ? 0.f : ts;
            #pragma unroll
            for (int b = 0; b < NB; b++) {
                float tt = ts / expf(tau_syn[b * 2 + c]);
                v += K_syn[(s * NB + b) * 2 + c] * tt * expf(-tt);
            }
        }
        ws[OFF_HP + idx] = v;
    } else if (idx < 30720) {                // ---- inT front/tail pad zeros
        int j = idx - 8640;
        const int PERROW = 552;              // 200 front + 352 tail
        int row = j / PERROW;
        int e = j - row * PERROW;
        int off = (e < 200) ? e : (200 + TDATA + (e - 200));
        ws[OFF_INT + (long)row * SROW + off] = 0.f;
    } else if (idx < 47104) {                // ---- e A-frags (bf16), 32 k-steps
        int j = idx - 30720;                 // 32*64*8 = 16384
        int step = j >> 9;
        int lane = (j >> 3) & 63;
        int jj = j & 7;
        int k = step * 16 + ((lane >> 5) << 3) + jj;
        int s = lane & 31;
        float v = (s < SUB && k < NE) ? C_e[s * NE + k] : 0.f;
        ((__hip_bfloat16*)(ws + OFF_BE))[j] = (__hip_bfloat16)v;
    } else {                                 // ---- i A-frags (bf16), 14 k-steps
        int j = idx - 47104;                 // 14*64*8 = 7168
        int step = j >> 9;
        int lane = (j >> 3) & 63;
        int jj = j & 7;
        int k = step * 16 + ((lane >> 5) << 3) + jj;
        int s = lane & 31;
        float v = (s < SUB && k < NI) ? C_i[s * NI + k] : 0.f;
        ((__hip_bfloat16*)(ws + OFF_BI))[j] = (__hip_bfloat16)v;
    }
}

// ---------------------------------------------------------------------------
// MFMA GEMM v10: PERSISTENT blocks + pipelined register staging.
//   v8/v9 evidence: clean reg-staged streaming caps at ~2.8 TB/s at BOTH
//   2 and 4 blocks/CU -> the cap is DUTY CYCLE, not concurrency: each
//   short-lived block issues one load burst then goes dark through
//   MFMA/reduce/store/teardown, and 6250 blocks = ~6 relaunch convoys/CU.
//   v10: 512 blocks (2/CU), each loops over ~9 e-tiles (or ~21 i-tiles).
//   Per iter: ds_write(tile g) [drains loads via dependency] -> B1 ->
//   ISSUE loads(g+1) -> MFMA(g) -> partial write -> B2 -> distributed
//   8-wave reduce + store.  Loads for g+1 are in flight across the whole
//   compute window; no block relaunch.  2 barriers/iter.
//   Tile: v9's verified bf16 layout+swizzle (byte ^= (row&7)<<4).  Scratch:
//   8 partials x 64 lanes x 16 f32, granule-swizzled ^((lane&7)<<2);
//   wave w reduces acc-regs {2w,2w+1} across all 8 partials -> 2 stores.
//   Named staging regs only (rule #20).  e/i split by block range,
//   byte-balanced (366/146).
// ---------------------------------------------------------------------------
template<int K, int NSTEP, int NF4, int RB>   // RB = LDS row stride in bytes
__device__ __forceinline__ void gemm10_body(
    const float* __restrict__ S, const float* __restrict__ wsA,
    float* __restrict__ inT, unsigned char* smem, int bid, int nbl, int tid)
{
    constexpr int NJ  = (NF4 + 511) / 512;   // e:8, i:4  float4s per thread
    constexpr int NAQ = (NSTEP + 7) / 8;     // e:4, i:2  k-steps per wave
    constexpr int F4R = K / 4;               // float4s per source row (125/50)
    constexpr int TB8 = (16 * NSTEP * 2 - 2 * K) / 8;  // tail b64s/row: e:3, i:2
    const int lane = tid & 63, wave = tid >> 6;
    const int n = lane & 31, h = lane >> 5;
    float* scr = (float*)(smem + 32768);     // 32KB partial scratch

    // A-frags -> registers ONCE (L2-hot region)
    const bf16x8* afr = (const bf16x8*)wsA;
    bf16x8 A[NAQ];
    #pragma unroll
    for (int q = 0; q < NAQ; q++) {
        int u = wave + 8 * q;
        if (u < NSTEP) A[q] = afr[u * 64 + lane];
    }

    // zero the k-tail ONCE (cols [K,16*NSTEP) never overwritten by staging)
    if (tid < 32 * TB8) {
        int r = tid / TB8, p = tid - r * TB8;
        int byt = (r * RB + 2 * K + 8 * p) ^ ((r & 7) << 4);
        *(unsigned long long*)(smem + byt) = 0ull;
    }

    int g = bid;
    const float4* src = (const float4*)(S + (long)g * (32 * K));
    float4 va, vb, vc, vd, ve, vf, vg, vh;

#define IDX10(J)  (tid + 512 * (J))
#define CI10(J)   (IDX10(J) < NF4 ? IDX10(J) : NF4 - 1)
#define GLD10() do {                                                        \
    va = src[CI10(0)]; vb = src[CI10(1)];                                   \
    vc = src[CI10(2)]; vd = src[CI10(3)];                                   \
    if constexpr (NJ == 8) {                                                \
        ve = src[CI10(4)]; vf = src[CI10(5)];                               \
        vg = src[CI10(6)]; vh = src[CI10(7)];                               \
    }                                                                       \
} while (0)
#define STG10(J, V) {                                                       \
    int idx = IDX10(J);                                                     \
    if ((J) < NJ - 1 || idx < NF4) {                                        \
        int r = idx / F4R;                                                  \
        int c4 = idx - r * F4R;                                             \
        int byt = (r * RB + c4 * 8) ^ ((r & 7) << 4);                       \
        bf16x4 bv;                                                          \
        bv[0] = (__bf16)V.x; bv[1] = (__bf16)V.y;                           \
        bv[2] = (__bf16)V.z; bv[3] = (__bf16)V.w;                           \
        *(bf16x4*)(smem + byt) = bv;                                        \
    }                                                                       \
}

    GLD10();                                 // prologue: tile g loads in flight

    for (;;) {
        // ---- stage tile g into LDS (cvt in regs; waits loads by dep) ----
        STG10(0, va); STG10(1, vb); STG10(2, vc); STG10(3, vd);
        if constexpr (NJ == 8) {
            STG10(4, ve); STG10(5, vf); STG10(6, vg); STG10(7, vh);
        }
        __syncthreads();                     // B1: tile visible

        // ---- issue NEXT tile's loads (overlap whole compute window) ----
        const int gn = g + nbl;
        const bool more = gn < NTILE;
        if (more) {
            src = (const float4*)(S + (long)gn * (32 * K));
            GLD10();
        }

        // ---- MFMA: wave w does k-steps u = w, w+8, ... ----
        f32x16 acc = {};
        #pragma unroll
        for (int q = 0; q < NAQ; q++) {
            int u = wave + 8 * q;
            if (u < NSTEP) {
                int byt = (n * RB + 16 * (2 * u + h)) ^ ((n & 7) << 4);
                bf16x8 b = *(const bf16x8*)(smem + byt);
                acc = __builtin_amdgcn_mfma_f32_32x32x16_bf16(A[q], b, acc, 0, 0, 0);
            }
        }

        // ---- partial write: granule-swizzled b128 ----
        #pragma unroll
        for (int q4 = 0; q4 < 4; q4++) {
            int w0 = ((wave * 64 + lane) * 16 + 4 * q4) ^ ((lane & 7) << 2);
            *(float4*)(scr + w0) = make_float4(acc[4 * q4],     acc[4 * q4 + 1],
                                               acc[4 * q4 + 2], acc[4 * q4 + 3]);
        }
        __syncthreads();                     // B2: partials visible (+ MFMA reads drained)

        // ---- distributed reduce: wave w sums regs {2w,2w+1} over p=0..7 ----
        {
            float s0 = 0.f, s1 = 0.f;
            #pragma unroll
            for (int p = 0; p < 8; p++) {
                int wb = (((p * 64 + lane) * 16 + 4 * (wave >> 1))
                          ^ ((lane & 7) << 2)) + 2 * (wave & 1);
                float2 v2 = *(const float2*)(scr + wb);
                s0 += v2.x; s1 += v2.y;
            }
            const long t = (long)g * 32 + n;
            const int r0i = 2 * wave, r1i = 2 * wave + 1;
            const int m0 = (r0i & 3) + 8 * (r0i >> 2) + 4 * h;
            const int m1 = (r1i & 3) + 8 * (r1i >> 2) + 4 * h;
            if (m0 < SUB) inT[(long)m0 * SROW + 200 + t] = s0;
            if (m1 < SUB) inT[(long)m1 * SROW + 200 + t] = s1;
        }

        if (!more) break;
        g = gn;
    }
#undef GLD10
#undef STG10
#undef IDX10
#undef CI10
}

__global__ __launch_bounds__(512, 4) void gemm_kernel(
    const float* __restrict__ Se, const float* __restrict__ Si,
    float* __restrict__ ws)
{
    __shared__ __align__(16) unsigned char smem[65536];  // 32KB tile + 32KB scratch
    const int tid = threadIdx.x;
    const int bid = blockIdx.x;
    if (bid < NBE)
        gemm10_body<NE, NSTEP_E, NF4_E, 1024>(Se, ws + OFF_BE, ws + OFF_INT,
                                              smem, bid, NBE, tid);
    else
        gemm10_body<NI, NSTEP_I, NF4_I, 512>(Si, ws + OFF_BI,
                                             ws + OFF_INT + (long)SUB * SROW,
                                             smem, bid - NBE, NBI, tid);
}

// ---------------------------------------------------------------------------
// Conv: round-0 version (benched clean; the rolling-window rewrite spilled).
// block = (s, 2048 t's); windows staged in LDS with i+(i>>5) swizzle;
// taps in LDS, broadcast ds_read_b128. Thread = 8 consecutive t's.
// ---------------------------------------------------------------------------
#define SW(i) ((i) + ((i) >> 5))

__global__ __launch_bounds__(256) void conv_kernel(
    const float* __restrict__ ws, float* __restrict__ out)
{
    __shared__ __align__(16) float W[2][2336];   // SW(2255)=2325 max
    __shared__ __align__(16) float HT[2][208];
    const int tid = threadIdx.x;
    const int s = blockIdx.y;
    const long t0 = (long)blockIdx.x * 2048;

    // stage windows: W[c][q] = row_c[t0 - 208 + q], q in [0,2256)
    for (int i = tid; i < 1128; i += 256) {
        int c = i >= 564;
        int i4 = i - c * 564;
        float4 v = *(const float4*)(ws + OFF_INT + (long)(c * SUB + s) * SROW
                                    + t0 - 8 + 4 * i4);
        int b = 4 * i4;
        int p = SW(b);                        // contiguous within aligned-4 runs
        W[c][p] = v.x; W[c][p + 1] = v.y; W[c][p + 2] = v.z; W[c][p + 3] = v.w;
    }
    if (tid < 104) {                          // taps: 2 channels x 208
        int c = tid >= 52;
        int j4 = (tid - c * 52) * 4;
        *(float4*)&HT[c][j4] =
            *(const float4*)(ws + OFF_HP + (c * SUB + s) * HROW + 8 + j4);
    }
    __syncthreads();

    float acc[8];
    #pragma unroll
    for (int r = 0; r < 8; r++) acc[r] = 0.f;

    #pragma unroll
    for (int c = 0; c < 2; c++) {
        #pragma unroll 2
        for (int g = 0; g < 26; g++) {
            int k0 = g << 3;
            int xb = (tid << 3) + 200 - k0;
            float x[16];
            #pragma unroll
            for (int q = 0; q < 16; q++) x[q] = W[c][SW(xb + q)];
            float h[8];
            *(float4*)&h[0] = *(const float4*)&HT[c][k0];
            *(float4*)&h[4] = *(const float4*)&HT[c][k0 + 4];
            #pragma unroll
            for (int j = 0; j < 8; j++)
                #pragma unroll
                for (int r = 0; r < 8; r++)
                    acc[r] += h[j] * x[8 + r - j];
        }
    }

    #pragma unroll
    for (int r = 0; r < 8; r++) {
        long t = t0 + 8 * tid + r;
        if (t < TDATA) out[t * SUB + s] = acc[r];
    }
}

// ---------------------------------------------------------------------------
extern "C" void kernel_launch(void* const* d_in, const int* in_sizes, int n_in,
                              void* d_out, int out_size, void* d_ws, size_t ws_size,
                              hipStream_t stream)
{
    const float* S_e     = (const float*)d_in[0];
    const float* S_i     = (const float*)d_in[1];
    const float* C_e     = (const float*)d_in[2];
    const float* C_i     = (const float*)d_in[3];
    const float* K_syn   = (const float*)d_in[4];
    const float* tau_syn = (const float*)d_in[5];
    const float* delta   = (const float*)d_in[6];
    float* out = (float*)d_out;
    float* ws  = (float*)d_ws;

    hipLaunchKernelGGL(setup_kernel, dim3(212), dim3(256), 0, stream,
                       C_e, C_i, K_syn, tau_syn, delta, ws);
    hipLaunchKernelGGL(gemm_kernel, dim3(NBE + NBI), dim3(512), 0, stream,
                       S_e, S_i, ws);
    hipLaunchKernelGGL(conv_kernel, dim3(49, SUB), dim3(256), 0, stream,
                       ws, out);
}